// Round 19
// baseline (56.769 us; speedup 1.0000x reference)
//
#include <hip/hip_runtime.h>

#define NRAYS 16384
#define SSTEPS 1024
#define GRES 128
#define NSAMP ((size_t)NRAYS * (size_t)SSTEPS)   // 16777216

typedef float floatx4 __attribute__((ext_vector_type(4)));   // native vec: OK for NT builtin

// R15 structure (one wave per ray, lane owns 4 consecutive samples per
// 256-sample chunk, coalesced 1KB float4 bursts) + non-temporal stores:
// output is write-once streaming data (268MB >> 32MB L2), bypass write-allocate.
extern "C" __global__ __launch_bounds__(256) void NeRFAccSampler_55791625175295_kernel(
    const float* __restrict__ rays_o,
    const float* __restrict__ rays_d,
    const float* __restrict__ jitter,
    const float* __restrict__ Wd,
    const float* __restrict__ bd,
    const unsigned char* __restrict__ binaries,
    float* __restrict__ out)
{
#pragma clang fp contract(off)
    const int tid  = blockIdx.x * 256 + (int)threadIdx.x;
    const int ray  = tid >> 6;
    const int lane = (int)threadIdx.x & 63;
    if (ray >= NRAYS) return;

    const float STEP = (float)(2.0 * 1.7320508075688772 / 1024.0);
    const float KEEP_THR = 9.2103405f;   // fl32(-ln 1e-4); excl < THR <=> T > 1e-4

    const float ox = rays_o[3 * ray + 0], oy = rays_o[3 * ray + 1], oz = rays_o[3 * ray + 2];
    const float dx = rays_d[3 * ray + 0], dy = rays_d[3 * ray + 1], dz = rays_d[3 * ray + 2];
    const float jit = jitter[ray];
    const float w0 = Wd[0], w1 = Wd[1], w2 = Wd[2], bb = bd[0];

    // slab test vs [-1,1]^3 (numpy-identical f32 rounding; inputs finite)
    const float ivx = 1.0f / dx, ivy = 1.0f / dy, ivz = 1.0f / dz;
    const float t0x = (-1.0f - ox) * ivx;
    const float t1x = ( 1.0f - ox) * ivx;
    const float t0y = (-1.0f - oy) * ivy;
    const float t1y = ( 1.0f - oy) * ivy;
    const float t0z = (-1.0f - oz) * ivz;
    const float t1z = ( 1.0f - oz) * ivz;
    const float tnx = t0x < t1x ? t0x : t1x, tXx = t0x > t1x ? t0x : t1x;
    const float tny = t0y < t1y ? t0y : t1y, tXy = t0y > t1y ? t0y : t1y;
    const float tnz = t0z < t1z ? t0z : t1z, tXz = t0z > t1z ? t0z : t1z;
    float t_near = tnx;
    if (tny > t_near) t_near = tny;
    if (tnz > t_near) t_near = tnz;
    if (t_near < 0.0f) t_near = 0.0f;
    float t_far = tXx;
    if (tXy < t_far) t_far = tXy;
    if (tXz < t_far) t_far = tXz;
    const bool hit = t_near < t_far;

    const size_t base  = (size_t)ray * (size_t)SSTEPS;
    const float  ray_f = (float)ray;
    const floatx4 o0v  = {ray_f, ray_f, ray_f, ray_f};

    float tau = 0.0f;   // carried transmittance integral (sum of sigma*STEP)

    for (int it = 0; it < 4; ++it) {
        const int s0 = (it << 8) + (lane << 2);   // first of this lane's 4 samples

        float ts[4], te[4], loc[4];
        bool  vld[4];
        float sum = 0.0f;

        #pragma unroll
        for (int k = 0; k < 4; ++k) {
            const float fi = (float)(s0 + k);
            const float t_start = t_near + (fi + jit) * STEP;
            const float t_end   = t_start + STEP;
            const float mid     = (t_start + t_end) * 0.5f;
            const float px = ox + dx * mid;
            const float py = oy + dy * mid;
            const float pz = oz + dz * mid;

            // cell = clip(floor((p+1)*64), 0, 127); clamp-then-trunc, NaN-safe
            float vx = (px + 1.0f) * 64.0f;
            float vy = (py + 1.0f) * 64.0f;
            float vz = (pz + 1.0f) * 64.0f;
            if (!(vx > 0.0f)) vx = 0.0f;
            if (vx > 127.0f)  vx = 127.0f;
            if (!(vy > 0.0f)) vy = 0.0f;
            if (vy > 127.0f)  vy = 127.0f;
            if (!(vz > 0.0f)) vz = 0.0f;
            if (vz > 127.0f)  vz = 127.0f;
            const int flat = (((int)vx * GRES) + (int)vy) * GRES + (int)vz;
            const bool occ = binaries[flat] != 0;

            const bool valid = occ && (t_end < t_far) && hit;

            float sig = ((px * w0 + py * w1) + pz * w2) + bb;
            if (sig < 0.0f) sig = 0.0f;
            const float sstep = (valid ? sig : 0.0f) * STEP;

            ts[k]  = t_start;
            te[k]  = t_end;
            vld[k] = valid;
            loc[k] = sum;          // lane-local exclusive prefix
            sum    = sum + sstep;
        }

        // wave-level inclusive scan of lane sums (6 shuffle steps)
        float run = sum;
        #pragma unroll
        for (int d = 1; d < 64; d <<= 1) {
            const float y = __shfl_up(run, d, 64);
            if (lane >= d) run += y;
        }
        const float exbase = tau + (run - sum);   // exclusive prefix entering this lane
        tau += __shfl(run, 63, 64);               // wave total -> carried tau

        floatx4 a1, a2, a3;
        #pragma unroll
        for (int k = 0; k < 4; ++k) {
            const float excl = exbase + loc[k];
            const bool keep  = vld[k] && (excl < KEEP_THR);
            a1[k] = keep ? ts[k] : 0.0f;
            a2[k] = keep ? te[k] : 0.0f;
            a3[k] = keep ? 1.0f  : 0.0f;
        }

        const size_t o = base + (size_t)s0;
        __builtin_nontemporal_store(o0v, reinterpret_cast<floatx4*>(&out[o]));
        __builtin_nontemporal_store(a1,  reinterpret_cast<floatx4*>(&out[NSAMP + o]));
        __builtin_nontemporal_store(a2,  reinterpret_cast<floatx4*>(&out[2 * NSAMP + o]));
        __builtin_nontemporal_store(a3,  reinterpret_cast<floatx4*>(&out[3 * NSAMP + o]));
    }
}

extern "C" void kernel_launch(void* const* d_in, const int* in_sizes, int n_in,
                              void* d_out, int out_size, void* d_ws, size_t ws_size,
                              hipStream_t stream) {
    const float* rays_o           = (const float*)d_in[0];
    const float* rays_d           = (const float*)d_in[1];
    const float* jitter           = (const float*)d_in[2];
    const float* Wd               = (const float*)d_in[3];
    const float* bd               = (const float*)d_in[4];
    const unsigned char* binaries = (const unsigned char*)d_in[5];
    float* out                    = (float*)d_out;

    // 4 waves (4 rays) per 256-thread block; 4096 blocks = 16384 waves.
    NeRFAccSampler_55791625175295_kernel<<<NRAYS / 4, 256, 0, stream>>>(
        rays_o, rays_d, jitter, Wd, bd, binaries, out);
}

// Round 20
// 49.178 us; speedup vs baseline: 1.1544x; 1.1544x over previous
//
#include <hip/hip_runtime.h>

#define NRAYS 16384
#define SSTEPS 1024
#define GRES 128
#define NSAMP ((size_t)NRAYS * (size_t)SSTEPS)   // 16777216

// FINAL (R15 structure — measured best at 49.8us, ~94% of achievable HBM BW):
// one 64-lane wave per ray; lane owns 4 consecutive samples per 256-sample
// chunk -> every float4 store is a contiguous 1KB wave burst. Carried-tau
// wave scan per chunk. f32 math, contraction off == numpy rounding on the
// keep-decision path; keep-test via monotone-equivalent threshold compare.
// Ledger: R16 lane-owns-16 layout -85%; R17 batched scans -3%; R19 NT stores -14%.
extern "C" __global__ __launch_bounds__(256) void NeRFAccSampler_55791625175295_kernel(
    const float* __restrict__ rays_o,
    const float* __restrict__ rays_d,
    const float* __restrict__ jitter,
    const float* __restrict__ Wd,
    const float* __restrict__ bd,
    const unsigned char* __restrict__ binaries,
    float* __restrict__ out)
{
#pragma clang fp contract(off)
    const int tid  = blockIdx.x * 256 + (int)threadIdx.x;
    const int ray  = tid >> 6;
    const int lane = (int)threadIdx.x & 63;
    if (ray >= NRAYS) return;

    const float STEP = (float)(2.0 * 1.7320508075688772 / 1024.0);
    const float KEEP_THR = 9.2103405f;   // fl32(-ln 1e-4); excl < THR <=> T > 1e-4

    const float ox = rays_o[3 * ray + 0], oy = rays_o[3 * ray + 1], oz = rays_o[3 * ray + 2];
    const float dx = rays_d[3 * ray + 0], dy = rays_d[3 * ray + 1], dz = rays_d[3 * ray + 2];
    const float jit = jitter[ray];
    const float w0 = Wd[0], w1 = Wd[1], w2 = Wd[2], bb = bd[0];

    // slab test vs [-1,1]^3 (numpy-identical f32 rounding; inputs finite)
    const float ivx = 1.0f / dx, ivy = 1.0f / dy, ivz = 1.0f / dz;
    const float t0x = (-1.0f - ox) * ivx;
    const float t1x = ( 1.0f - ox) * ivx;
    const float t0y = (-1.0f - oy) * ivy;
    const float t1y = ( 1.0f - oy) * ivy;
    const float t0z = (-1.0f - oz) * ivz;
    const float t1z = ( 1.0f - oz) * ivz;
    const float tnx = t0x < t1x ? t0x : t1x, tXx = t0x > t1x ? t0x : t1x;
    const float tny = t0y < t1y ? t0y : t1y, tXy = t0y > t1y ? t0y : t1y;
    const float tnz = t0z < t1z ? t0z : t1z, tXz = t0z > t1z ? t0z : t1z;
    float t_near = tnx;
    if (tny > t_near) t_near = tny;
    if (tnz > t_near) t_near = tnz;
    if (t_near < 0.0f) t_near = 0.0f;
    float t_far = tXx;
    if (tXy < t_far) t_far = tXy;
    if (tXz < t_far) t_far = tXz;
    const bool hit = t_near < t_far;

    const size_t base  = (size_t)ray * (size_t)SSTEPS;
    const float  ray_f = (float)ray;
    const float4 o0v   = make_float4(ray_f, ray_f, ray_f, ray_f);

    float tau = 0.0f;   // carried transmittance integral (sum of sigma*STEP)

    for (int it = 0; it < 4; ++it) {
        const int s0 = (it << 8) + (lane << 2);   // first of this lane's 4 samples

        float ts[4], te[4], loc[4];
        bool  vld[4];
        float sum = 0.0f;

        #pragma unroll
        for (int k = 0; k < 4; ++k) {
            const float fi = (float)(s0 + k);
            const float t_start = t_near + (fi + jit) * STEP;
            const float t_end   = t_start + STEP;
            const float mid     = (t_start + t_end) * 0.5f;
            const float px = ox + dx * mid;
            const float py = oy + dy * mid;
            const float pz = oz + dz * mid;

            // cell = clip(floor((p+1)*64), 0, 127); clamp-then-trunc, NaN-safe
            float vx = (px + 1.0f) * 64.0f;
            float vy = (py + 1.0f) * 64.0f;
            float vz = (pz + 1.0f) * 64.0f;
            if (!(vx > 0.0f)) vx = 0.0f;
            if (vx > 127.0f)  vx = 127.0f;
            if (!(vy > 0.0f)) vy = 0.0f;
            if (vy > 127.0f)  vy = 127.0f;
            if (!(vz > 0.0f)) vz = 0.0f;
            if (vz > 127.0f)  vz = 127.0f;
            const int flat = (((int)vx * GRES) + (int)vy) * GRES + (int)vz;
            const bool occ = binaries[flat] != 0;

            const bool valid = occ && (t_end < t_far) && hit;

            float sig = ((px * w0 + py * w1) + pz * w2) + bb;
            if (sig < 0.0f) sig = 0.0f;
            const float sstep = (valid ? sig : 0.0f) * STEP;

            ts[k]  = t_start;
            te[k]  = t_end;
            vld[k] = valid;
            loc[k] = sum;          // lane-local exclusive prefix
            sum    = sum + sstep;
        }

        // wave-level inclusive scan of lane sums (6 shuffle steps)
        float run = sum;
        #pragma unroll
        for (int d = 1; d < 64; d <<= 1) {
            const float y = __shfl_up(run, d, 64);
            if (lane >= d) run += y;
        }
        const float exbase = tau + (run - sum);   // exclusive prefix entering this lane
        tau += __shfl(run, 63, 64);               // wave total -> carried tau

        float a1[4], a2[4], a3[4];
        #pragma unroll
        for (int k = 0; k < 4; ++k) {
            const float excl = exbase + loc[k];
            const bool keep  = vld[k] && (excl < KEEP_THR);
            a1[k] = keep ? ts[k] : 0.0f;
            a2[k] = keep ? te[k] : 0.0f;
            a3[k] = keep ? 1.0f  : 0.0f;
        }

        const size_t o = base + (size_t)s0;
        *reinterpret_cast<float4*>(&out[o])             = o0v;
        *reinterpret_cast<float4*>(&out[NSAMP + o])     = make_float4(a1[0], a1[1], a1[2], a1[3]);
        *reinterpret_cast<float4*>(&out[2 * NSAMP + o]) = make_float4(a2[0], a2[1], a2[2], a2[3]);
        *reinterpret_cast<float4*>(&out[3 * NSAMP + o]) = make_float4(a3[0], a3[1], a3[2], a3[3]);
    }
}

extern "C" void kernel_launch(void* const* d_in, const int* in_sizes, int n_in,
                              void* d_out, int out_size, void* d_ws, size_t ws_size,
                              hipStream_t stream) {
    const float* rays_o           = (const float*)d_in[0];
    const float* rays_d           = (const float*)d_in[1];
    const float* jitter           = (const float*)d_in[2];
    const float* Wd               = (const float*)d_in[3];
    const float* bd               = (const float*)d_in[4];
    const unsigned char* binaries = (const unsigned char*)d_in[5];
    float* out                    = (float*)d_out;

    // 4 waves (4 rays) per 256-thread block; 4096 blocks = 16384 waves.
    NeRFAccSampler_55791625175295_kernel<<<NRAYS / 4, 256, 0, stream>>>(
        rays_o, rays_d, jitter, Wd, bd, binaries, out);
}